// Round 5
// baseline (513.630 us; speedup 1.0000x reference)
//
#include <hip/hip_runtime.h>
#include <math.h>

#define EPSF 1e-7f
#define GCHUNK 10
#define NSEG 16

// Ballot-compaction of valid GT boxes into LDS (order-preserving). blockDim must be 256.
// Also records per-p validity in svalid.
__device__ __forceinline__ int compact_valid(const float4* __restrict__ bt_n, int P, int tid,
                                             float4* scb, int* sidx, float* sarea,
                                             unsigned char* svalid, int* wcnt) {
    float4 b = make_float4(0.f, 0.f, 0.f, 0.f);
    bool v = false;
    if (tid < P) {
        b = bt_n[tid];
        v = (b.x > 0.f || b.y > 0.f || b.z > 0.f || b.w > 0.f);
        svalid[tid] = v ? 1 : 0;
    }
    unsigned long long m = __ballot(v);
    int lane = tid & 63, wv = tid >> 6;
    if (lane == 0) wcnt[wv] = __popcll(m);
    int posn = __popcll(m & ((1ull << lane) - 1ull));
    __syncthreads();
    int base = 0;
    for (int w = 0; w < wv; w++) base += wcnt[w];
    int V = wcnt[0] + wcnt[1] + wcnt[2] + wcnt[3];
    if (v) {
        scb[base + posn] = b;
        sidx[base + posn] = tid;
        sarea[base + posn] = (b.z - b.x) * (b.w - b.y);
    }
    __syncthreads();
    return V;
}

// Per-(segment, image): for every valid GT, best (max-IoU, smallest anchor idx on tie)
// over this segment's anchors. Division-free fraction compare. Butterfly wave merge.
// Block (0,0) also zeroes the done counter for k_fused's last-block reduction.
__global__ __launch_bounds__(256) void k_gt_all(const float4* __restrict__ bbox_true,
                                                const float4* __restrict__ anchors,
                                                float* __restrict__ pn, float* __restrict__ pd,
                                                int* __restrict__ pi,
                                                unsigned int* __restrict__ done,
                                                int N, int P, int A) {
    __shared__ float4 scb[256];
    __shared__ int    sidx[256];
    __shared__ float  sarea[256];
    __shared__ unsigned char svalid[256];
    __shared__ int    wcnt[4];
    __shared__ float  mn[4][GCHUNK], md[4][GCHUNK];
    __shared__ int    mi[4][GCHUNK];

    int n = blockIdx.y, seg = blockIdx.x, tid = threadIdx.x;
    if (seg == 0 && n == 0 && tid == 0) *done = 0u;
    int lane = tid & 63, wv = tid >> 6;
    int V = compact_valid(bbox_true + (size_t)n * P, P, tid, scb, sidx, sarea, svalid, wcnt);
    int len = (A + NSEG - 1) / NSEG;
    int a0 = seg * len;
    int a1 = a0 + len < A ? a0 + len : A;

    for (int c0 = 0; c0 < V; c0 += GCHUNK) {
        int G = V - c0 < GCHUNK ? V - c0 : GCHUNK;
        float bn[GCHUNK], bd[GCHUNK];
        int   bi[GCHUNK];
#pragma unroll
        for (int g = 0; g < GCHUNK; g++) { bn[g] = -1.f; bd[g] = 1.f; bi[g] = 0x7fffffff; }
        for (int a = a0 + tid; a < a1; a += 256) {
            float4 an = anchors[a];
            float aa = (an.z - an.x) * (an.w - an.y);
#pragma unroll
            for (int g = 0; g < GCHUNK; g++) {
                if (g < G) {
                    float4 b = scb[c0 + g];
                    float iw = fminf(an.z, b.z) - fmaxf(an.x, b.x); iw = iw > 0.f ? iw : 0.f;
                    float ih = fminf(an.w, b.w) - fmaxf(an.y, b.y); ih = ih > 0.f ? ih : 0.f;
                    float inter = iw * ih;
                    float den = aa + sarea[c0 + g] - inter + EPSF;
                    if (inter * bd[g] > bn[g] * den) { bn[g] = inter; bd[g] = den; bi[g] = a; }
                }
            }
        }
        // wave-64 butterfly merge
        for (int off = 32; off > 0; off >>= 1) {
#pragma unroll
            for (int g = 0; g < GCHUNK; g++) {
                float on = __shfl_xor(bn[g], off, 64);
                float od = __shfl_xor(bd[g], off, 64);
                int   oi = __shfl_xor(bi[g], off, 64);
                float l = on * bd[g], r = bn[g] * od;
                if (l > r || (l == r && oi < bi[g])) { bn[g] = on; bd[g] = od; bi[g] = oi; }
            }
        }
        if (lane == 0) {
#pragma unroll
            for (int g = 0; g < GCHUNK; g++) { mn[wv][g] = bn[g]; md[wv][g] = bd[g]; mi[wv][g] = bi[g]; }
        }
        __syncthreads();
        if (tid < G) {
            float Bn = -1.f, Bd = 1.f; int Bi = 0x7fffffff;
            for (int w = 0; w < 4; w++) {
                float cn = mn[w][tid], cd = md[w][tid];
                int ci = mi[w][tid];
                float l = cn * Bd, r = Bn * cd;
                if (l > r || (l == r && ci < Bi)) { Bn = cn; Bd = cd; Bi = ci; }
            }
            int p = sidx[c0 + tid];
            size_t o = ((size_t)n * P + p) * NSEG + seg;
            pn[o] = Bn; pd[o] = Bd; pi[o] = Bi;
        }
        __syncthreads();
    }
}

// Everything else in one dispatch:
//  - per-block: merge segment partials, compute JAX-scatter closed form -> LDS flags
//  - per-anchor assignment + all three losses + block reduce -> partial row
//  - last finished block reduces all partials, applies avg_factor + guard, writes out.
__global__ __launch_bounds__(256) void k_fused(const float4* __restrict__ bbox_true,
                                               const float4* __restrict__ anchors,
                                               const float* __restrict__ conf,
                                               const float* __restrict__ logit,
                                               const float4* __restrict__ bbox_pred,
                                               const float* __restrict__ y_true,
                                               const float* __restrict__ pn,
                                               const float* __restrict__ pd,
                                               const int* __restrict__ pi,
                                               double* __restrict__ partial,
                                               unsigned int* __restrict__ done,
                                               float* __restrict__ out,
                                               int N, int P, int A, int C, int BX) {
    int tid = threadIdx.x;
    int n = blockIdx.y;
    int a = blockIdx.x * blockDim.x + tid;
    int lane = tid & 63, wv = tid >> 6;

    __shared__ float4 scb[256];
    __shared__ int    sidx[256];
    __shared__ float  sarea[256];
    __shared__ unsigned char svalid[256];
    __shared__ int    wcnt[4];
    __shared__ int    sflag[256];
    __shared__ int    gb[256];
    __shared__ unsigned char lqs[256];

    sflag[tid] = -1;  // before compact_valid's internal __syncthreads
    int V = compact_valid(bbox_true + (size_t)n * P, P, tid, scb, sidx, sarea, svalid, wcnt);

    // merge per-GT segment partials (rational compare, first-anchor tie-break)
    if (tid < P) {
        int g = 0; bool lq = false;
        if (svalid[tid]) {
            float Bn = -1.f, Bd = 1.f; int Bi = 0x7fffffff;
            const float* qn = pn + ((size_t)n * P + tid) * NSEG;
            const float* qd = pd + ((size_t)n * P + tid) * NSEG;
            const int*   qi = pi + ((size_t)n * P + tid) * NSEG;
            for (int s = 0; s < NSEG; s++) {
                float cn = qn[s], cd = qd[s]; int ci = qi[s];
                if (cn >= 0.f) {
                    float l = cn * Bd, r = Bn * cd;
                    if (l > r || (l == r && ci < Bi)) { Bn = cn; Bd = cd; Bi = ci; }
                }
            }
            g = Bi;
            lq = (Bn > 0.f);   // gt_max > 0  <=>  max intersection > 0
        }
        gb[tid] = g; lqs[tid] = lq ? 1 : 0;
    }
    __syncthreads();
    // closed-form JAX scatter (serial-in-p, last-wins, pos sticky): winner per anchor
    if (tid < P) {
        int myidx = gb[tid];
        bool anylq = false, islast = true;
        for (int q = 0; q < P; q++) {
            if (gb[q] == myidx) {
                if (lqs[q]) anylq = true;
                if (q > tid) islast = false;
            }
        }
        if (islast && anylq) {
            int local = myidx - blockIdx.x * 256;
            if (local >= 0 && local < 256) sflag[local] = lqs[tid] ? tid : -2;
        }
    }
    __syncthreads();

    double sc = 0.0, cl = 0.0, bb = 0.0, pc = 0.0;
    if (a < A) {
        float4 an = anchors[a];
        float aa = (an.z - an.x) * (an.w - an.y);
        float bn = -1.f, bd = 1.f; int bi = 0;
        for (int k = 0; k < V; k++) {
            float4 b = scb[k];
            float iw = fminf(an.z, b.z) - fmaxf(an.x, b.x); iw = iw > 0.f ? iw : 0.f;
            float ih = fminf(an.w, b.w) - fmaxf(an.y, b.y); ih = ih > 0.f ? ih : 0.f;
            float inter = iw * ih;
            float den = aa + sarea[k] - inter + EPSF;
            if (inter * bd > bn * den) { bn = inter; bd = den; bi = sidx[k]; }
        }
        bool pos, neg;
        if (V > 0) { pos = (bn >= 0.5f * bd); neg = (bn < 0.4f * bd); }
        else       { pos = false; neg = true; }
        int ov = sflag[tid];
        pos = pos || (ov != -1);
        neg = neg && !pos;
        int t = (ov >= 0) ? ov : bi;

        size_t o = (size_t)n * A + a;
        float p = conf[o];
        p = fminf(fmaxf(p, EPSF), 1.f - EPSF);
        if (pos || neg) sc = (double)(pos ? -logf(p) : -logf(1.f - p));
        if (pos) {
            pc = 1.0;
            const float* yt = y_true + ((size_t)n * P + t) * C;
            const float* lg = logit + o * C;
            float s = 0.f;
            for (int c = 0; c < C; c++) {
                float tl = yt[c];
                float q = fminf(fmaxf(lg[c], EPSF), 1.f - EPSF);
                float pt = tl * q + (1.f - tl) * (1.f - q);
                float at = tl * 0.25f + (1.f - tl) * 0.75f;
                float om = 1.f - pt;
                s += -at * om * om * logf(pt);
            }
            cl = (double)s;
            float4 bt = bbox_true[(size_t)n * P + t];
            float4 bp = bbox_pred[o];
            float ix1 = fmaxf(bt.x, bp.x), iy1 = fmaxf(bt.y, bp.y);
            float ix2 = fminf(bt.z, bp.z), iy2 = fminf(bt.w, bp.w);
            float iw = ix2 - ix1; iw = iw > 0.f ? iw : 0.f;
            float ih = iy2 - iy1; ih = ih > 0.f ? ih : 0.f;
            float inter = iw * ih;
            float wt = bt.z - bt.x, ht = bt.w - bt.y;
            float wp = bp.z - bp.x, hp = bp.w - bp.y;
            float uni = wt * ht + wp * hp - inter + EPSF;
            float iou = inter / uni;
            float cw = fmaxf(bt.z, bp.z) - fminf(bt.x, bp.x);
            float ch = fmaxf(bt.w, bp.w) - fminf(bt.y, bp.y);
            float c2 = cw * cw + ch * ch + EPSF;
            float dx = bt.x + bt.z - bp.x - bp.z;
            float dy = bt.y + bt.w - bp.y - bp.w;
            float rho2 = (dx * dx + dy * dy) * 0.25f;
            float dd = atanf(wt / (ht + EPSF)) - atanf(wp / (hp + EPSF));
            float vv = 0.40528473456935109f * dd * dd;   // 4/pi^2
            float al = vv / (1.f - iou + vv + EPSF);
            bb = (double)(1.f - iou + rho2 / c2 + al * vv);
        }
    }

    for (int off = 32; off > 0; off >>= 1) {
        sc += __shfl_down(sc, off, 64);
        cl += __shfl_down(cl, off, 64);
        bb += __shfl_down(bb, off, 64);
        pc += __shfl_down(pc, off, 64);
    }
    __shared__ double sred[4][4];
    if (lane == 0) { sred[wv][0] = sc; sred[wv][1] = cl; sred[wv][2] = bb; sred[wv][3] = pc; }
    __syncthreads();
    __shared__ int amLast;
    if (tid == 0) {
        double r0 = 0, r1 = 0, r2 = 0, r3 = 0;
        for (int w = 0; w < 4; w++) {
            r0 += sred[w][0]; r1 += sred[w][1]; r2 += sred[w][2]; r3 += sred[w][3];
        }
        double* row = partial + ((size_t)n * BX + blockIdx.x) * 4;
        row[0] = r0; row[1] = r1; row[2] = r2; row[3] = r3;
        __threadfence();
        unsigned int old = atomicAdd(done, 1u);
        amLast = (old == (unsigned int)(N * BX) - 1u) ? 1 : 0;
    }
    __syncthreads();
    if (!amLast) return;
    __threadfence();

    // ---- final reduction (runs in exactly one block) ----
    __shared__ double sh[256];
    __shared__ double res[3];
    __shared__ double shn[64];
    double s0 = 0, s1 = 0, s2 = 0;
    int total = N * BX;
    for (int i = tid; i < total; i += 256) {
        const double* r = partial + (size_t)i * 4;
        s0 += r[0]; s1 += r[1]; s2 += r[2];
    }
    double vals[3] = {s0, s1, s2};
    for (int k = 0; k < 3; k++) {
        sh[tid] = vals[k];
        __syncthreads();
        for (int s = 128; s > 0; s >>= 1) {
            if (tid < s) sh[tid] += sh[tid + s];
            __syncthreads();
        }
        if (tid == 0) res[k] = sh[0];
        __syncthreads();
    }
    int chunks = 256 / N;
    double pcs = 0;
    int nn = tid / chunks, cc = tid % chunks;
    if (nn < N) {
        int per = (BX + chunks - 1) / chunks;
        int j0 = cc * per, j1 = (j0 + per < BX) ? j0 + per : BX;
        for (int j = j0; j < j1; j++) pcs += partial[((size_t)nn * BX + j) * 4 + 3];
    }
    sh[tid] = pcs;
    __syncthreads();
    if (tid < N) {
        double s = 0;
        for (int c2 = 0; c2 < chunks; c2++) s += sh[tid * chunks + c2];
        shn[tid] = s > 1.0 ? s : 1.0;
    }
    __syncthreads();
    if (tid == 0) {
        double avg = 0;
        for (int i = 0; i < N; i++) avg += shn[i];
        for (int k = 0; k < 3; k++) {
            double x = res[k] / avg;
            if (isnan(x) || isinf(x)) x = 0.0;
            out[k] = (float)x;
        }
    }
}

extern "C" void kernel_launch(void* const* d_in, const int* in_sizes, int n_in,
                              void* d_out, int out_size, void* d_ws, size_t ws_size,
                              hipStream_t stream) {
    const float* y_true    = (const float*)d_in[0];
    const float* bbox_true = (const float*)d_in[1];
    const float* conf      = (const float*)d_in[2];
    const float* logit     = (const float*)d_in[3];
    const float* bboxp     = (const float*)d_in[4];
    const float* anchors   = (const float*)d_in[5];

    int A = in_sizes[5] / 4;            // anchors: (A,4)
    int N = in_sizes[2] / A;            // conf:    (N,A,1)
    int P = in_sizes[1] / (4 * N);      // bbox_true: (N,P,4)
    int C = in_sizes[0] / (N * P);      // y_true: (N,P,C)

    int BX = (A + 255) / 256;

    char* w = (char*)d_ws;
    auto alloc = [&](size_t bytes) -> void* {
        void* r = (void*)w;
        w += (bytes + 15) & ~(size_t)15;
        return r;
    };
    float*  pn      = (float*)alloc(sizeof(float) * (size_t)N * P * NSEG);
    float*  pd      = (float*)alloc(sizeof(float) * (size_t)N * P * NSEG);
    int*    pi      = (int*)alloc(sizeof(int) * (size_t)N * P * NSEG);
    double* partial = (double*)alloc(sizeof(double) * (size_t)N * BX * 4);
    unsigned int* done = (unsigned int*)alloc(sizeof(unsigned int));

    dim3 gS(NSEG, N);
    k_gt_all<<<gS, 256, 0, stream>>>((const float4*)bbox_true, (const float4*)anchors,
                                     pn, pd, pi, done, N, P, A);

    dim3 gA(BX, N);
    k_fused<<<gA, 256, 0, stream>>>((const float4*)bbox_true, (const float4*)anchors,
                                    conf, logit, (const float4*)bboxp, y_true,
                                    pn, pd, pi, partial, done, (float*)d_out,
                                    N, P, A, C, BX);
}

// Round 6
// 500.005 us; speedup vs baseline: 1.0273x; 1.0273x over previous
//
#include <hip/hip_runtime.h>
#include <math.h>

#define EPSF 1e-7f
#define GCHUNK 10
#define NSEG 16

// Ballot-compaction of valid GT boxes into LDS (order-preserving). blockDim must be 256.
__device__ __forceinline__ int compact_valid(const float4* __restrict__ bt_n, int P, int tid,
                                             float4* scb, int* sidx, float* sarea, int* wcnt) {
    float4 b = make_float4(0.f, 0.f, 0.f, 0.f);
    bool v = false;
    if (tid < P) {
        b = bt_n[tid];
        v = (b.x > 0.f || b.y > 0.f || b.z > 0.f || b.w > 0.f);
    }
    unsigned long long m = __ballot(v);
    int lane = tid & 63, wv = tid >> 6;
    if (lane == 0) wcnt[wv] = __popcll(m);
    int posn = __popcll(m & ((1ull << lane) - 1ull));
    __syncthreads();
    int base = 0;
    for (int w = 0; w < wv; w++) base += wcnt[w];
    int V = wcnt[0] + wcnt[1] + wcnt[2] + wcnt[3];
    if (v) {
        scb[base + posn] = b;
        sidx[base + posn] = tid;
        sarea[base + posn] = (b.z - b.x) * (b.w - b.y);
    }
    __syncthreads();
    return V;
}

// Per-(segment, image): for every valid GT, best (max-IoU, smallest anchor idx on tie)
// over this segment's anchors. Division-free fraction compare. Butterfly wave merge.
// Block (0,0) zeroes the done counter for k_fused's last-block reduction.
__global__ __launch_bounds__(256) void k_gt_all(const float4* __restrict__ bbox_true,
                                                const float4* __restrict__ anchors,
                                                float* __restrict__ pn, float* __restrict__ pd,
                                                int* __restrict__ pi,
                                                unsigned int* __restrict__ done,
                                                int N, int P, int A) {
    __shared__ float4 scb[256];
    __shared__ int    sidx[256];
    __shared__ float  sarea[256];
    __shared__ int    wcnt[4];
    __shared__ float  mn[4][GCHUNK], md[4][GCHUNK];
    __shared__ int    mi[4][GCHUNK];

    int n = blockIdx.y, seg = blockIdx.x, tid = threadIdx.x;
    if (seg == 0 && n == 0 && tid == 0) *done = 0u;
    int lane = tid & 63, wv = tid >> 6;
    int V = compact_valid(bbox_true + (size_t)n * P, P, tid, scb, sidx, sarea, wcnt);
    int len = (A + NSEG - 1) / NSEG;
    int a0 = seg * len;
    int a1 = a0 + len < A ? a0 + len : A;

    for (int c0 = 0; c0 < V; c0 += GCHUNK) {
        int G = V - c0 < GCHUNK ? V - c0 : GCHUNK;
        float bn[GCHUNK], bd[GCHUNK];
        int   bi[GCHUNK];
#pragma unroll
        for (int g = 0; g < GCHUNK; g++) { bn[g] = -1.f; bd[g] = 1.f; bi[g] = 0x7fffffff; }
        for (int a = a0 + tid; a < a1; a += 256) {
            float4 an = anchors[a];
            float aa = (an.z - an.x) * (an.w - an.y);
#pragma unroll
            for (int g = 0; g < GCHUNK; g++) {
                if (g < G) {
                    float4 b = scb[c0 + g];
                    float iw = fminf(an.z, b.z) - fmaxf(an.x, b.x); iw = iw > 0.f ? iw : 0.f;
                    float ih = fminf(an.w, b.w) - fmaxf(an.y, b.y); ih = ih > 0.f ? ih : 0.f;
                    float inter = iw * ih;
                    float den = aa + sarea[c0 + g] - inter + EPSF;
                    if (inter * bd[g] > bn[g] * den) { bn[g] = inter; bd[g] = den; bi[g] = a; }
                }
            }
        }
        for (int off = 32; off > 0; off >>= 1) {
#pragma unroll
            for (int g = 0; g < GCHUNK; g++) {
                float on = __shfl_xor(bn[g], off, 64);
                float od = __shfl_xor(bd[g], off, 64);
                int   oi = __shfl_xor(bi[g], off, 64);
                float l = on * bd[g], r = bn[g] * od;
                if (l > r || (l == r && oi < bi[g])) { bn[g] = on; bd[g] = od; bi[g] = oi; }
            }
        }
        if (lane == 0) {
#pragma unroll
            for (int g = 0; g < GCHUNK; g++) { mn[wv][g] = bn[g]; md[wv][g] = bd[g]; mi[wv][g] = bi[g]; }
        }
        __syncthreads();
        if (tid < G) {
            float Bn = -1.f, Bd = 1.f; int Bi = 0x7fffffff;
            for (int w = 0; w < 4; w++) {
                float cn = mn[w][tid], cd = md[w][tid];
                int ci = mi[w][tid];
                float l = cn * Bd, r = Bn * cd;
                if (l > r || (l == r && ci < Bi)) { Bn = cn; Bd = cd; Bi = ci; }
            }
            int p = sidx[c0 + tid];
            size_t o = ((size_t)n * P + p) * NSEG + seg;
            pn[o] = Bn; pd[o] = Bd; pi[o] = Bi;
        }
        __syncthreads();
    }
}

// Merge segment partials per GT, emit JAX scatter result as a COMPACT list:
// entry (anchor, val) exists iff any lowq p targets that anchor; val = p_last if the
// last targeting p is lowq, else -2 (pos sticky, ti reverts to anchor's own argmax).
__global__ __launch_bounds__(128) void k_scatter2(const float4* __restrict__ bbox_true,
                                                  const float* __restrict__ pn,
                                                  const float* __restrict__ pd,
                                                  const int* __restrict__ pi,
                                                  int* __restrict__ ovr_cnt,
                                                  int2* __restrict__ ovr_list,
                                                  int N, int P, int A) {
    int n = blockIdx.x, p = threadIdx.x;
    __shared__ int gb[128];
    __shared__ unsigned char lqs[128];
    __shared__ int cnt;
    if (p == 0) cnt = 0;
    if (p < P) {
        float4 b = bbox_true[(size_t)n * P + p];
        bool valid = (b.x > 0.f || b.y > 0.f || b.z > 0.f || b.w > 0.f);
        int g = 0; bool lq = false;
        if (valid) {
            float Bn = -1.f, Bd = 1.f; int Bi = 0x7fffffff;
            const float* qn = pn + ((size_t)n * P + p) * NSEG;
            const float* qd = pd + ((size_t)n * P + p) * NSEG;
            const int*   qi = pi + ((size_t)n * P + p) * NSEG;
            for (int s = 0; s < NSEG; s++) {
                float cn = qn[s], cd = qd[s]; int ci = qi[s];
                if (cn >= 0.f) {
                    float l = cn * Bd, r = Bn * cd;
                    if (l > r || (l == r && ci < Bi)) { Bn = cn; Bd = cd; Bi = ci; }
                }
            }
            g = Bi;
            lq = (Bn > 0.f);   // gt_max > 0  <=>  max intersection > 0
        }
        gb[p] = g; lqs[p] = lq ? 1 : 0;
    }
    __syncthreads();
    if (p < P) {
        int myidx = gb[p];
        bool anylq = false, islast = true;
        for (int q = 0; q < P; q++) {
            if (gb[q] == myidx) {
                if (lqs[q]) anylq = true;
                if (q > p) islast = false;
            }
        }
        if (islast && anylq) {
            int s = atomicAdd(&cnt, 1);
            ovr_list[(size_t)n * P + s] = make_int2(myidx, lqs[p] ? p : -2);
        }
    }
    __syncthreads();
    if (p == 0) ovr_cnt[n] = cnt;
}

// Fused per-anchor assignment + score + CIoU; positive focal loss processed
// wave-cooperatively (coalesced class loads, parallel logf). Last block reduces.
__global__ __launch_bounds__(256) void k_fused(const float4* __restrict__ bbox_true,
                                               const float4* __restrict__ anchors,
                                               const float* __restrict__ conf,
                                               const float* __restrict__ logit,
                                               const float4* __restrict__ bbox_pred,
                                               const float* __restrict__ y_true,
                                               const int* __restrict__ ovr_cnt,
                                               const int2* __restrict__ ovr_list,
                                               double* __restrict__ partial,
                                               unsigned int* __restrict__ done,
                                               float* __restrict__ out,
                                               int N, int P, int A, int C, int BX) {
    int tid = threadIdx.x;
    int n = blockIdx.y;
    int a = blockIdx.x * blockDim.x + tid;
    int lane = tid & 63, wv = tid >> 6;

    __shared__ float4 scb[256];
    __shared__ int    sidx[256];
    __shared__ float  sarea[256];
    __shared__ int    wcnt[4];
    __shared__ int    sflag[256];
    __shared__ int    plist[256];   // packed positives: local_a | (t << 8)
    __shared__ int    pw4[4];

    sflag[tid] = -1;  // before compact_valid's internal __syncthreads
    int V = compact_valid(bbox_true + (size_t)n * P, P, tid, scb, sidx, sarea, wcnt);
    int cnt = ovr_cnt[n];
    if (tid < cnt) {
        int2 e = ovr_list[(size_t)n * P + tid];
        int local = e.x - blockIdx.x * 256;
        if (local >= 0 && local < 256) sflag[local] = e.y;
    }
    __syncthreads();

    double sc = 0.0, cl = 0.0, bb = 0.0, pc = 0.0;
    bool pos = false;
    int t = 0;
    if (a < A) {
        float4 an = anchors[a];
        float aa = (an.z - an.x) * (an.w - an.y);
        float bn = -1.f, bd = 1.f; int bi = 0;
        for (int k = 0; k < V; k++) {
            float4 b = scb[k];
            float iw = fminf(an.z, b.z) - fmaxf(an.x, b.x); iw = iw > 0.f ? iw : 0.f;
            float ih = fminf(an.w, b.w) - fmaxf(an.y, b.y); ih = ih > 0.f ? ih : 0.f;
            float inter = iw * ih;
            float den = aa + sarea[k] - inter + EPSF;
            if (inter * bd > bn * den) { bn = inter; bd = den; bi = sidx[k]; }
        }
        bool neg;
        if (V > 0) { pos = (bn >= 0.5f * bd); neg = (bn < 0.4f * bd); }
        else       { pos = false; neg = true; }
        int ov = sflag[tid];
        pos = pos || (ov != -1);
        neg = neg && !pos;
        t = (ov >= 0) ? ov : bi;

        size_t o = (size_t)n * A + a;
        float p = conf[o];
        p = fminf(fmaxf(p, EPSF), 1.f - EPSF);
        if (pos || neg) sc = (double)(-logf(pos ? p : 1.f - p));
        if (pos) {
            pc = 1.0;
            // CIoU (cheap scalar, no log)
            float4 bt = bbox_true[(size_t)n * P + t];
            float4 bp = bbox_pred[o];
            float ix1 = fmaxf(bt.x, bp.x), iy1 = fmaxf(bt.y, bp.y);
            float ix2 = fminf(bt.z, bp.z), iy2 = fminf(bt.w, bp.w);
            float iw = ix2 - ix1; iw = iw > 0.f ? iw : 0.f;
            float ih = iy2 - iy1; ih = ih > 0.f ? ih : 0.f;
            float inter = iw * ih;
            float wt = bt.z - bt.x, ht = bt.w - bt.y;
            float wp = bp.z - bp.x, hp = bp.w - bp.y;
            float uni = wt * ht + wp * hp - inter + EPSF;
            float iou = inter / uni;
            float cw = fmaxf(bt.z, bp.z) - fminf(bt.x, bp.x);
            float ch = fmaxf(bt.w, bp.w) - fminf(bt.y, bp.y);
            float c2 = cw * cw + ch * ch + EPSF;
            float dx = bt.x + bt.z - bp.x - bp.z;
            float dy = bt.y + bt.w - bp.y - bp.w;
            float rho2 = (dx * dx + dy * dy) * 0.25f;
            float dd = atanf(wt / (ht + EPSF)) - atanf(wp / (hp + EPSF));
            float vv = 0.40528473456935109f * dd * dd;   // 4/pi^2
            float al = vv / (1.f - iou + vv + EPSF);
            bb = (double)(1.f - iou + rho2 / c2 + al * vv);
        }
    }

    // ---- compact positives into LDS, process focal loss wave-cooperatively ----
    {
        unsigned long long m = __ballot(pos);
        if (lane == 0) pw4[wv] = __popcll(m);
        int posn = __popcll(m & ((1ull << lane) - 1ull));
        __syncthreads();
        int base = 0;
        for (int w = 0; w < wv; w++) base += pw4[w];
        int npos = pw4[0] + pw4[1] + pw4[2] + pw4[3];
        if (pos) plist[base + posn] = tid | (t << 8);
        __syncthreads();

        for (int i = wv; i < npos; i += 4) {
            int e = plist[i];
            int la = e & 255, tt = e >> 8;
            size_t o = (size_t)n * A + (size_t)blockIdx.x * 256 + la;
            const float* lg = logit + o * C;
            const float* yt = y_true + ((size_t)n * P + tt) * C;
            float s = 0.f;
            for (int c = lane; c < C; c += 64) {
                float tl = yt[c];
                float q = fminf(fmaxf(lg[c], EPSF), 1.f - EPSF);
                float pt = tl * q + (1.f - tl) * (1.f - q);
                float at = tl * 0.25f + (1.f - tl) * 0.75f;
                float om = 1.f - pt;
                s += -at * om * om * logf(pt);
            }
            for (int off = 32; off > 0; off >>= 1) s += __shfl_down(s, off, 64);
            if (lane == 0) cl += (double)s;
        }
    }

    // block reduction
    for (int off = 32; off > 0; off >>= 1) {
        sc += __shfl_down(sc, off, 64);
        cl += __shfl_down(cl, off, 64);
        bb += __shfl_down(bb, off, 64);
        pc += __shfl_down(pc, off, 64);
    }
    __shared__ double sred[4][4];
    if (lane == 0) { sred[wv][0] = sc; sred[wv][1] = cl; sred[wv][2] = bb; sred[wv][3] = pc; }
    __syncthreads();
    __shared__ int amLast;
    if (tid == 0) {
        double r0 = 0, r1 = 0, r2 = 0, r3 = 0;
        for (int w = 0; w < 4; w++) {
            r0 += sred[w][0]; r1 += sred[w][1]; r2 += sred[w][2]; r3 += sred[w][3];
        }
        double* row = partial + ((size_t)n * BX + blockIdx.x) * 4;
        row[0] = r0; row[1] = r1; row[2] = r2; row[3] = r3;
        __threadfence();
        unsigned int old = atomicAdd(done, 1u);
        amLast = (old == (unsigned int)(N * BX) - 1u) ? 1 : 0;
    }
    __syncthreads();
    if (!amLast) return;
    __threadfence();

    // ---- final reduction (exactly one block) ----
    __shared__ double sh[256];
    __shared__ double res[3];
    __shared__ double shn[64];
    double s0 = 0, s1 = 0, s2 = 0;
    int total = N * BX;
    for (int i = tid; i < total; i += 256) {
        const double* r = partial + (size_t)i * 4;
        s0 += r[0]; s1 += r[1]; s2 += r[2];
    }
    double vals[3] = {s0, s1, s2};
    for (int k = 0; k < 3; k++) {
        sh[tid] = vals[k];
        __syncthreads();
        for (int s = 128; s > 0; s >>= 1) {
            if (tid < s) sh[tid] += sh[tid + s];
            __syncthreads();
        }
        if (tid == 0) res[k] = sh[0];
        __syncthreads();
    }
    int chunks = 256 / N;
    double pcs = 0;
    int nn = tid / chunks, cc = tid % chunks;
    if (nn < N) {
        int per = (BX + chunks - 1) / chunks;
        int j0 = cc * per, j1 = (j0 + per < BX) ? j0 + per : BX;
        for (int j = j0; j < j1; j++) pcs += partial[((size_t)nn * BX + j) * 4 + 3];
    }
    sh[tid] = pcs;
    __syncthreads();
    if (tid < N) {
        double s = 0;
        for (int c2 = 0; c2 < chunks; c2++) s += sh[tid * chunks + c2];
        shn[tid] = s > 1.0 ? s : 1.0;
    }
    __syncthreads();
    if (tid == 0) {
        double avg = 0;
        for (int i = 0; i < N; i++) avg += shn[i];
        for (int k = 0; k < 3; k++) {
            double x = res[k] / avg;
            if (isnan(x) || isinf(x)) x = 0.0;
            out[k] = (float)x;
        }
    }
}

extern "C" void kernel_launch(void* const* d_in, const int* in_sizes, int n_in,
                              void* d_out, int out_size, void* d_ws, size_t ws_size,
                              hipStream_t stream) {
    const float* y_true    = (const float*)d_in[0];
    const float* bbox_true = (const float*)d_in[1];
    const float* conf      = (const float*)d_in[2];
    const float* logit     = (const float*)d_in[3];
    const float* bboxp     = (const float*)d_in[4];
    const float* anchors   = (const float*)d_in[5];

    int A = in_sizes[5] / 4;            // anchors: (A,4)
    int N = in_sizes[2] / A;            // conf:    (N,A,1)
    int P = in_sizes[1] / (4 * N);      // bbox_true: (N,P,4)
    int C = in_sizes[0] / (N * P);      // y_true: (N,P,C)

    int BX = (A + 255) / 256;

    char* w = (char*)d_ws;
    auto alloc = [&](size_t bytes) -> void* {
        void* r = (void*)w;
        w += (bytes + 15) & ~(size_t)15;
        return r;
    };
    float*  pn      = (float*)alloc(sizeof(float) * (size_t)N * P * NSEG);
    float*  pd      = (float*)alloc(sizeof(float) * (size_t)N * P * NSEG);
    int*    pi      = (int*)alloc(sizeof(int) * (size_t)N * P * NSEG);
    int*    ovr_cnt = (int*)alloc(sizeof(int) * (size_t)N);
    int2*   ovr_list= (int2*)alloc(sizeof(int2) * (size_t)N * P);
    double* partial = (double*)alloc(sizeof(double) * (size_t)N * BX * 4);
    unsigned int* done = (unsigned int*)alloc(sizeof(unsigned int));

    dim3 gS(NSEG, N);
    k_gt_all<<<gS, 256, 0, stream>>>((const float4*)bbox_true, (const float4*)anchors,
                                     pn, pd, pi, done, N, P, A);

    k_scatter2<<<N, 128, 0, stream>>>((const float4*)bbox_true, pn, pd, pi,
                                      ovr_cnt, ovr_list, N, P, A);

    dim3 gA(BX, N);
    k_fused<<<gA, 256, 0, stream>>>((const float4*)bbox_true, (const float4*)anchors,
                                    conf, logit, (const float4*)bboxp, y_true,
                                    ovr_cnt, ovr_list, partial, done, (float*)d_out,
                                    N, P, A, C, BX);
}

// Round 7
// 426.261 us; speedup vs baseline: 1.2050x; 1.1730x over previous
//
#include <hip/hip_runtime.h>
#include <math.h>

#define EPSF 1e-7f
#define GCHUNK 10
#define NSEG 16

// Ballot-compaction of valid GT boxes into LDS (order-preserving). blockDim must be 256.
// Also writes inverse map sinv[original_p] = compacted slot (valid p only).
__device__ __forceinline__ int compact_valid(const float4* __restrict__ bt_n, int P, int tid,
                                             float4* scb, int* sidx, float* sarea,
                                             int* sinv, int* wcnt) {
    float4 b = make_float4(0.f, 0.f, 0.f, 0.f);
    bool v = false;
    if (tid < P) {
        b = bt_n[tid];
        v = (b.x > 0.f || b.y > 0.f || b.z > 0.f || b.w > 0.f);
    }
    unsigned long long m = __ballot(v);
    int lane = tid & 63, wv = tid >> 6;
    if (lane == 0) wcnt[wv] = __popcll(m);
    int posn = __popcll(m & ((1ull << lane) - 1ull));
    __syncthreads();
    int base = 0;
    for (int w = 0; w < wv; w++) base += wcnt[w];
    int V = wcnt[0] + wcnt[1] + wcnt[2] + wcnt[3];
    if (v) {
        scb[base + posn] = b;
        sidx[base + posn] = tid;
        sarea[base + posn] = (b.z - b.x) * (b.w - b.y);
        if (sinv) sinv[tid] = base + posn;
    }
    __syncthreads();
    return V;
}

// Per-(segment, image): for every valid GT, best (max-IoU, smallest anchor idx on tie)
// over this segment's anchors. Division-free fraction compare. Butterfly wave merge.
__global__ __launch_bounds__(256) void k_gt_all(const float4* __restrict__ bbox_true,
                                                const float4* __restrict__ anchors,
                                                float* __restrict__ pn, float* __restrict__ pd,
                                                int* __restrict__ pi,
                                                int N, int P, int A) {
    __shared__ float4 scb[256];
    __shared__ int    sidx[256];
    __shared__ float  sarea[256];
    __shared__ int    wcnt[4];
    __shared__ float  mn[4][GCHUNK], md[4][GCHUNK];
    __shared__ int    mi[4][GCHUNK];

    int n = blockIdx.y, seg = blockIdx.x, tid = threadIdx.x;
    int lane = tid & 63, wv = tid >> 6;
    int V = compact_valid(bbox_true + (size_t)n * P, P, tid, scb, sidx, sarea, nullptr, wcnt);
    int len = (A + NSEG - 1) / NSEG;
    int a0 = seg * len;
    int a1 = a0 + len < A ? a0 + len : A;

    for (int c0 = 0; c0 < V; c0 += GCHUNK) {
        int G = V - c0 < GCHUNK ? V - c0 : GCHUNK;
        float bn[GCHUNK], bd[GCHUNK];
        int   bi[GCHUNK];
#pragma unroll
        for (int g = 0; g < GCHUNK; g++) { bn[g] = -1.f; bd[g] = 1.f; bi[g] = 0x7fffffff; }
        for (int a = a0 + tid; a < a1; a += 256) {
            float4 an = anchors[a];
            float aa = (an.z - an.x) * (an.w - an.y);
#pragma unroll
            for (int g = 0; g < GCHUNK; g++) {
                if (g < G) {
                    float4 b = scb[c0 + g];
                    float iw = fminf(an.z, b.z) - fmaxf(an.x, b.x); iw = iw > 0.f ? iw : 0.f;
                    float ih = fminf(an.w, b.w) - fmaxf(an.y, b.y); ih = ih > 0.f ? ih : 0.f;
                    float inter = iw * ih;
                    float den = aa + sarea[c0 + g] - inter + EPSF;
                    if (inter * bd[g] > bn[g] * den) { bn[g] = inter; bd[g] = den; bi[g] = a; }
                }
            }
        }
        for (int off = 32; off > 0; off >>= 1) {
#pragma unroll
            for (int g = 0; g < GCHUNK; g++) {
                float on = __shfl_xor(bn[g], off, 64);
                float od = __shfl_xor(bd[g], off, 64);
                int   oi = __shfl_xor(bi[g], off, 64);
                float l = on * bd[g], r = bn[g] * od;
                if (l > r || (l == r && oi < bi[g])) { bn[g] = on; bd[g] = od; bi[g] = oi; }
            }
        }
        if (lane == 0) {
#pragma unroll
            for (int g = 0; g < GCHUNK; g++) { mn[wv][g] = bn[g]; md[wv][g] = bd[g]; mi[wv][g] = bi[g]; }
        }
        __syncthreads();
        if (tid < G) {
            float Bn = -1.f, Bd = 1.f; int Bi = 0x7fffffff;
            for (int w = 0; w < 4; w++) {
                float cn = mn[w][tid], cd = md[w][tid];
                int ci = mi[w][tid];
                float l = cn * Bd, r = Bn * cd;
                if (l > r || (l == r && ci < Bi)) { Bn = cn; Bd = cd; Bi = ci; }
            }
            int p = sidx[c0 + tid];
            size_t o = ((size_t)n * P + p) * NSEG + seg;
            pn[o] = Bn; pd[o] = Bd; pi[o] = Bi;
        }
        __syncthreads();
    }
}

// Merge segment partials per GT, emit JAX scatter result as a COMPACT list:
// entry (anchor, val) exists iff any lowq p targets that anchor; val = p_last if the
// last targeting p is lowq, else -2 (pos sticky, ti reverts to anchor's own argmax).
__global__ __launch_bounds__(128) void k_scatter2(const float4* __restrict__ bbox_true,
                                                  const float* __restrict__ pn,
                                                  const float* __restrict__ pd,
                                                  const int* __restrict__ pi,
                                                  int* __restrict__ ovr_cnt,
                                                  int2* __restrict__ ovr_list,
                                                  int N, int P, int A) {
    int n = blockIdx.x, p = threadIdx.x;
    __shared__ int gb[128];
    __shared__ unsigned char lqs[128];
    __shared__ int cnt;
    if (p == 0) cnt = 0;
    if (p < P) {
        float4 b = bbox_true[(size_t)n * P + p];
        bool valid = (b.x > 0.f || b.y > 0.f || b.z > 0.f || b.w > 0.f);
        int g = 0; bool lq = false;
        if (valid) {
            float Bn = -1.f, Bd = 1.f; int Bi = 0x7fffffff;
            const float* qn = pn + ((size_t)n * P + p) * NSEG;
            const float* qd = pd + ((size_t)n * P + p) * NSEG;
            const int*   qi = pi + ((size_t)n * P + p) * NSEG;
            for (int s = 0; s < NSEG; s++) {
                float cn = qn[s], cd = qd[s]; int ci = qi[s];
                if (cn >= 0.f) {
                    float l = cn * Bd, r = Bn * cd;
                    if (l > r || (l == r && ci < Bi)) { Bn = cn; Bd = cd; Bi = ci; }
                }
            }
            g = Bi;
            lq = (Bn > 0.f);   // gt_max > 0  <=>  max intersection > 0
        }
        gb[p] = g; lqs[p] = lq ? 1 : 0;
    }
    __syncthreads();
    if (p < P) {
        int myidx = gb[p];
        bool anylq = false, islast = true;
        for (int q = 0; q < P; q++) {
            if (gb[q] == myidx) {
                if (lqs[q]) anylq = true;
                if (q > p) islast = false;
            }
        }
        if (islast && anylq) {
            int s = atomicAdd(&cnt, 1);
            ovr_list[(size_t)n * P + s] = make_int2(myidx, lqs[p] ? p : -2);
        }
    }
    __syncthreads();
    if (p == 0) ovr_cnt[n] = cnt;
}

// Fused per-anchor assignment + score + CIoU (+ wave-cooperative focal).
// All global loads whose address is known at entry are issued BEFORE the first
// barrier so their L2/L3-cold miss latency overlaps compaction + assign compute.
__global__ __launch_bounds__(256) void k_fused(const float4* __restrict__ bbox_true,
                                               const float4* __restrict__ anchors,
                                               const float* __restrict__ conf,
                                               const float* __restrict__ logit,
                                               const float4* __restrict__ bbox_pred,
                                               const float* __restrict__ y_true,
                                               const int* __restrict__ ovr_cnt,
                                               const int2* __restrict__ ovr_list,
                                               double* __restrict__ partial,
                                               int N, int P, int A, int C, int BX) {
    int tid = threadIdx.x;
    int n = blockIdx.y;
    int a = blockIdx.x * blockDim.x + tid;
    int lane = tid & 63, wv = tid >> 6;

    __shared__ float4 scb[256];
    __shared__ int    sidx[256];
    __shared__ float  sarea[256];
    __shared__ int    sinv[256];
    __shared__ int    wcnt[4];
    __shared__ int    sflag[256];
    __shared__ int    plist[256];   // packed positives: local_a | (t << 8)
    __shared__ int    pw4[4];

    // ---- prefetch: issue all entry-known global loads before any barrier ----
    size_t o = (size_t)n * A + (size_t)(a < A ? a : A - 1);
    float  pconf = conf[o];
    float4 anch  = anchors[a < A ? a : A - 1];
    float4 bp    = bbox_pred[o];
    int    cnt   = ovr_cnt[n];
    int2   epre  = make_int2(0, 0);
    if (tid < P) epre = ovr_list[(size_t)n * P + tid];

    sflag[tid] = -1;  // before compact_valid's internal __syncthreads
    int V = compact_valid(bbox_true + (size_t)n * P, P, tid, scb, sidx, sarea, sinv, wcnt);
    if (tid < cnt) {   // entries [0,cnt) are valid; epre junk beyond cnt never used
        int local = epre.x - blockIdx.x * 256;
        if (local >= 0 && local < 256) sflag[local] = epre.y;
    }
    __syncthreads();

    double sc = 0.0, cl = 0.0, bb = 0.0, pc = 0.0;
    bool pos = false;
    int t = 0;
    if (a < A) {
        float aa = (anch.z - anch.x) * (anch.w - anch.y);
        float bn = -1.f, bd = 1.f; int bi = 0;
        float4 bbest = make_float4(0.f, 0.f, 0.f, 0.f);
        for (int k = 0; k < V; k++) {
            float4 b = scb[k];
            float iw = fminf(anch.z, b.z) - fmaxf(anch.x, b.x); iw = iw > 0.f ? iw : 0.f;
            float ih = fminf(anch.w, b.w) - fmaxf(anch.y, b.y); ih = ih > 0.f ? ih : 0.f;
            float inter = iw * ih;
            float den = aa + sarea[k] - inter + EPSF;
            if (inter * bd > bn * den) { bn = inter; bd = den; bi = sidx[k]; bbest = b; }
        }
        bool neg;
        if (V > 0) { pos = (bn >= 0.5f * bd); neg = (bn < 0.4f * bd); }
        else       { pos = false; neg = true; }
        int ov = sflag[tid];
        pos = pos || (ov != -1);
        neg = neg && !pos;
        t = (ov >= 0) ? ov : bi;

        float p = fminf(fmaxf(pconf, EPSF), 1.f - EPSF);
        if (pos || neg) sc = (double)(-logf(pos ? p : 1.f - p));
        if (pos) {
            pc = 1.0;
            // GT box comes from LDS (already staged) — no global re-gather
            float4 bt = (ov >= 0) ? scb[sinv[ov]] : bbest;
            float ix1 = fmaxf(bt.x, bp.x), iy1 = fmaxf(bt.y, bp.y);
            float ix2 = fminf(bt.z, bp.z), iy2 = fminf(bt.w, bp.w);
            float iw = ix2 - ix1; iw = iw > 0.f ? iw : 0.f;
            float ih = iy2 - iy1; ih = ih > 0.f ? ih : 0.f;
            float inter = iw * ih;
            float wt = bt.z - bt.x, ht = bt.w - bt.y;
            float wp = bp.z - bp.x, hp = bp.w - bp.y;
            float uni = wt * ht + wp * hp - inter + EPSF;
            float iou = inter / uni;
            float cw = fmaxf(bt.z, bp.z) - fminf(bt.x, bp.x);
            float ch = fmaxf(bt.w, bp.w) - fminf(bt.y, bp.y);
            float c2 = cw * cw + ch * ch + EPSF;
            float dx = bt.x + bt.z - bp.x - bp.z;
            float dy = bt.y + bt.w - bp.y - bp.w;
            float rho2 = (dx * dx + dy * dy) * 0.25f;
            float dd = atanf(wt / (ht + EPSF)) - atanf(wp / (hp + EPSF));
            float vv = 0.40528473456935109f * dd * dd;   // 4/pi^2
            float al = vv / (1.f - iou + vv + EPSF);
            bb = (double)(1.f - iou + rho2 / c2 + al * vv);
        }
    }

    // ---- compact positives into LDS, process focal loss wave-cooperatively ----
    {
        unsigned long long m = __ballot(pos);
        if (lane == 0) pw4[wv] = __popcll(m);
        int posn = __popcll(m & ((1ull << lane) - 1ull));
        __syncthreads();
        int base = 0;
        for (int w = 0; w < wv; w++) base += pw4[w];
        int npos = pw4[0] + pw4[1] + pw4[2] + pw4[3];
        if (pos) plist[base + posn] = tid | (t << 8);
        __syncthreads();

        for (int i = wv; i < npos; i += 4) {
            int e = plist[i];
            int la = e & 255, tt = e >> 8;
            size_t oo = (size_t)n * A + (size_t)blockIdx.x * 256 + la;
            const float* lg = logit + oo * C;
            const float* yt = y_true + ((size_t)n * P + tt) * C;
            float s = 0.f;
            for (int c = lane; c < C; c += 64) {
                float tl = yt[c];
                float q = fminf(fmaxf(lg[c], EPSF), 1.f - EPSF);
                float pt = tl * q + (1.f - tl) * (1.f - q);
                float at = tl * 0.25f + (1.f - tl) * 0.75f;
                float om = 1.f - pt;
                s += -at * om * om * logf(pt);
            }
            for (int off = 32; off > 0; off >>= 1) s += __shfl_down(s, off, 64);
            if (lane == 0) cl += (double)s;
        }
    }

    // block reduction
    for (int off = 32; off > 0; off >>= 1) {
        sc += __shfl_down(sc, off, 64);
        cl += __shfl_down(cl, off, 64);
        bb += __shfl_down(bb, off, 64);
        pc += __shfl_down(pc, off, 64);
    }
    __shared__ double sred[4][4];
    if (lane == 0) { sred[wv][0] = sc; sred[wv][1] = cl; sred[wv][2] = bb; sred[wv][3] = pc; }
    __syncthreads();
    if (tid == 0) {
        double r0 = 0, r1 = 0, r2 = 0, r3 = 0;
        for (int w = 0; w < 4; w++) {
            r0 += sred[w][0]; r1 += sred[w][1]; r2 += sred[w][2]; r3 += sred[w][3];
        }
        double* row = partial + ((size_t)n * BX + blockIdx.x) * 4;
        row[0] = r0; row[1] = r1; row[2] = r2; row[3] = r3;
    }
}

__global__ __launch_bounds__(256) void k_final(const double* __restrict__ partial,
                                               float* __restrict__ out, int N, int BX) {
    const int FT = 256;
    int tid = threadIdx.x;
    __shared__ double sh[FT];
    __shared__ double res[3];
    __shared__ double shn[64];

    double s0 = 0, s1 = 0, s2 = 0;
    int total = N * BX;
    for (int i = tid; i < total; i += FT) {
        const double* r = partial + (size_t)i * 4;
        s0 += r[0]; s1 += r[1]; s2 += r[2];
    }
    double vals[3] = {s0, s1, s2};
    for (int k = 0; k < 3; k++) {
        sh[tid] = vals[k];
        __syncthreads();
        for (int s = 128; s > 0; s >>= 1) {
            if (tid < s) sh[tid] += sh[tid + s];
            __syncthreads();
        }
        if (tid == 0) res[k] = sh[0];
        __syncthreads();
    }
    int chunks = FT / N;
    double pcs = 0;
    int n = tid / chunks, c = tid % chunks;
    if (n < N) {
        int per = (BX + chunks - 1) / chunks;
        int j0 = c * per, j1 = (j0 + per < BX) ? j0 + per : BX;
        for (int j = j0; j < j1; j++) pcs += partial[((size_t)n * BX + j) * 4 + 3];
    }
    sh[tid] = pcs;
    __syncthreads();
    if (tid < N) {
        double s = 0;
        for (int c2 = 0; c2 < chunks; c2++) s += sh[tid * chunks + c2];
        shn[tid] = s > 1.0 ? s : 1.0;
    }
    __syncthreads();
    if (tid == 0) {
        double avg = 0;
        for (int i = 0; i < N; i++) avg += shn[i];
        for (int k = 0; k < 3; k++) {
            double x = res[k] / avg;
            if (isnan(x) || isinf(x)) x = 0.0;
            out[k] = (float)x;
        }
    }
}

extern "C" void kernel_launch(void* const* d_in, const int* in_sizes, int n_in,
                              void* d_out, int out_size, void* d_ws, size_t ws_size,
                              hipStream_t stream) {
    const float* y_true    = (const float*)d_in[0];
    const float* bbox_true = (const float*)d_in[1];
    const float* conf      = (const float*)d_in[2];
    const float* logit     = (const float*)d_in[3];
    const float* bboxp     = (const float*)d_in[4];
    const float* anchors   = (const float*)d_in[5];

    int A = in_sizes[5] / 4;            // anchors: (A,4)
    int N = in_sizes[2] / A;            // conf:    (N,A,1)
    int P = in_sizes[1] / (4 * N);      // bbox_true: (N,P,4)
    int C = in_sizes[0] / (N * P);      // y_true: (N,P,C)

    int BX = (A + 255) / 256;

    char* w = (char*)d_ws;
    auto alloc = [&](size_t bytes) -> void* {
        void* r = (void*)w;
        w += (bytes + 15) & ~(size_t)15;
        return r;
    };
    float*  pn      = (float*)alloc(sizeof(float) * (size_t)N * P * NSEG);
    float*  pd      = (float*)alloc(sizeof(float) * (size_t)N * P * NSEG);
    int*    pi      = (int*)alloc(sizeof(int) * (size_t)N * P * NSEG);
    int*    ovr_cnt = (int*)alloc(sizeof(int) * (size_t)N);
    int2*   ovr_list= (int2*)alloc(sizeof(int2) * (size_t)N * P);
    double* partial = (double*)alloc(sizeof(double) * (size_t)N * BX * 4);

    dim3 gS(NSEG, N);
    k_gt_all<<<gS, 256, 0, stream>>>((const float4*)bbox_true, (const float4*)anchors,
                                     pn, pd, pi, N, P, A);

    k_scatter2<<<N, 128, 0, stream>>>((const float4*)bbox_true, pn, pd, pi,
                                      ovr_cnt, ovr_list, N, P, A);

    dim3 gA(BX, N);
    k_fused<<<gA, 256, 0, stream>>>((const float4*)bbox_true, (const float4*)anchors,
                                    conf, logit, (const float4*)bboxp, y_true,
                                    ovr_cnt, ovr_list, partial, N, P, A, C, BX);

    k_final<<<1, 256, 0, stream>>>(partial, (float*)d_out, N, BX);
}